// Round 14
// baseline (91.106 us; speedup 1.0000x reference)
//
#include <hip/hip_runtime.h>
#include <hip/hip_fp16.h>
#include <stdint.h>

#define N 512
#define NA 180
#define TD 64           // detectors per block
#define TI 512          // i-values per block (8 phases of 64) -> 1 block per (d-tile, a)
#define TW 100          // LDS tile pitch in pair-dwords (100%32=4 -> rows shift banks)
#define TILE_DW (37 * 256)          // 9472 dw = 37888 B -> 4 blocks/CU @ 512 thr
#define PP 708          // padded pair-image pitch (dwords)
#define PR 704          // padded pair-image rows
#define POFF 96         // padded index of image row/col 0

// d_ws float-offsets
#define WS_IMGPB  0
#define WS_IMGTPB (PR * PP)                 // 498432
#define WS_TAB    (2 * PR * PP)             // 996864 (16B aligned)
#define WS_FLAGS  (WS_TAB + 4 * NA)

typedef _Float16 hh2 __attribute__((ext_vector_type(2)));
union H2U { uint32_t u; hh2 h; };

__device__ __forceinline__ hh2 cvt_pkrtz(float a, float b) {
    return __builtin_bit_cast(hh2, __builtin_amdgcn_cvt_pkrtz(a, b));
}

__device__ __forceinline__ void load16_to_lds(const uint32_t* g, uint32_t* l) {
    __builtin_amdgcn_global_load_lds(
        (const __attribute__((address_space(1))) void*)g,
        (__attribute__((address_space(3))) void*)l,
        16 /*bytes*/, 0 /*offset*/, 0 /*aux*/);
}

// Tiled pad (512 thr): block (bx,by) covers a 64x64 padded region; builds the
// padded fp16-pair image (imgPB[r][c] = (h(I[r][c]), h(I[r][c+1]))) and its
// transpose, all accesses coalesced. Also the per-angle table. (out needs no
// zeroing: radon fully overwrites it with plain stores.)
__global__ __launch_bounds__(512) void pad_kernel(const float* __restrict__ img,
                                                  const int* __restrict__ angles,
                                                  uint32_t* __restrict__ imgPB,
                                                  uint32_t* __restrict__ imgTPB,
                                                  float4* __restrict__ tab,
                                                  int* __restrict__ flags) {
    __shared__ float lds[65 * 66];   // pitch 66
    const int tid  = threadIdx.x;
    const int lane = tid & 63;
    const int wq   = tid >> 6;       // 0..7
    const int bx = blockIdx.x, by = blockIdx.y;
    const int b  = by * 11 + bx;

    if (b == 120 && tid < NA) {
        float t = (float)angles[tid] * 0.017453292519943295f;
        float si = sinf(t), co = cosf(t);
        int useT = fabsf(si) > fabsf(co);
        float4 e;
        if (useT) { e.x = co; e.y = -si; e.z = si; e.w = co; }
        else      { e.x = si; e.y = co;  e.z = co; e.w = -si; }
        tab[tid] = e;                // (au, bus, av, bvs)
        flags[tid] = useT;
    }

    // stage 65x65 of the padded image: padded coords (by*64+r, bx*64+c)
    for (int idx = tid; idx < 65 * 65; idx += 512) {
        int r = idx / 65, cc = idx - r * 65;
        int y = by * 64 + r - POFF, x = bx * 64 + cc - POFF;
        bool in = ((unsigned)y < N) && ((unsigned)x < N);
        lds[r * 66 + cc] = in ? img[y * N + x] : 0.0f;
    }
    __syncthreads();
#pragma unroll
    for (int j = 0; j < 8; ++j) {
        int r = wq * 8 + j;
        float v0 = lds[r * 66 + lane], v1 = lds[r * 66 + lane + 1];
        __half2 h = __halves2half2(__float2half(v0), __float2half(v1));
        imgPB[(size_t)(by * 64 + r) * PP + bx * 64 + lane] = *(uint32_t*)&h;
        float t0 = lds[lane * 66 + r], t1 = lds[(lane + 1) * 66 + r];
        __half2 ht = __halves2half2(__float2half(t0), __float2half(t1));
        imgTPB[(size_t)(bx * 64 + r) * PP + by * 64 + lane] = *(uint32_t*)&ht;
    }
}

// One block = (1 angle, 64 detectors, ALL 512 i): eight phases of (stage
// fp16-pair tile, sample 8 i/wave). Pitch 100 (=4 mod 32) de-aliases tile
// rows across LDS banks for both ds_read2 and staging writes.
__global__ __launch_bounds__(512, 8) void radon_kernel(const uint32_t* __restrict__ imgPB,
                                                       const uint32_t* __restrict__ imgTPB,
                                                       const float4* __restrict__ tab,
                                                       const int* __restrict__ flags,
                                                       float* __restrict__ out) {
    __shared__ uint32_t tile[TILE_DW];

    const int tid  = threadIdx.x;
    const int lane = tid & 63;
    const int wave = tid >> 6;           // 0..7
    const int d0 = blockIdx.x * TD;
    const int a  = blockIdx.y;
    const int rot = (blockIdx.x + blockIdx.y) & 7;   // de-phase co-resident blocks

    const float c = 255.5f;
    const float4 tb = tab[a];
    const float au = tb.x, bus = tb.y, av = tb.z, bvs = tb.w;

    // d-extremes of the affine offset (fixed for the whole block)
    const float xc0 = (float)d0 - c, xc1 = (float)(d0 + TD - 1) - c;
    const float buA = fmaf(bus, xc0, c), buB = fmaf(bus, xc1, c);
    const float bvA = fmaf(bvs, xc0, c), bvB = fmaf(bvs, xc1, c);
    const float buMin = fminf(buA, buB), buMax = fmaxf(buA, buB);
    const float bvMin = fminf(bvA, bvB), bvMax = fmaxf(bvA, bvB);

    const uint32_t* __restrict__ src = flags[a] ? imgTPB : imgPB;

    // per-lane affine offsets (shared by all phases)
    const float xcl = (float)(d0 + lane) - c;
    const float buLb = fmaf(bus, xcl, c);
    const float bvLb = fmaf(bvs, xcl, c);

    // incremental staging address bases (per lane, shared by all phases)
    const int t0g  = wave * 256 + (lane << 2);   // dword index into tile
    const int q0   = t0g / TW;
    const int c0   = t0g - q0 * TW;              // multiple of 4 (t0g,TW = 0 mod 4)
    const int goff0 = q0 * PP + c0;              // dword offset from gbase

    float s = 0.0f;
    for (int p8 = 0; p8 < 8; ++p8) {
        const int ph = (p8 + rot) & 7;
        const int ip = ph * 64;
        const float fi0 = (float)ip - c, fi1 = (float)(ip + 63) - c;
        const float fiLoU = (au >= 0.0f) ? fi0 : fi1, fiHiU = (au >= 0.0f) ? fi1 : fi0;
        const float fiLoV = (av >= 0.0f) ? fi0 : fi1, fiHiV = (av >= 0.0f) ? fi1 : fi0;
        const float umin = fmaf(au, fiLoU, buMin), umax = fmaf(au, fiHiU, buMax);
        const float vmin = fmaf(av, fiLoV, bvMin), vmax = fmaf(av, fiHiV, bvMax);
        // block-uniform: skipping barriers is legal (all threads agree)
        if (umin > (float)N || umax < -1.0f || vmin > (float)N || vmax < -1.0f)
            continue;

        // >=1-texel margins; for live phases umin >= -90.3 so cols/rows stay
        // inside the 96-apron (no OOB). u_local <= 94.5 < 99 fits pitch 100.
        const int ub0 = (((int)floorf(umin)) - 1) & ~3;
        const int vb  = ((int)floorf(vmin)) - 1;
        // rows touched: vb .. floor(vmax)+2  (bottom ulp margin)
        const int rows = ((int)floorf(vmax)) + 3 - vb;       // <= 94
        const int nch  = (rows * TW + 255) >> 8;             // <= 37, block-uniform

        __syncthreads();                 // WAR: prev live phase sampling done
        {
            const uint32_t* gb = src + (vb + POFF) * PP + (ub0 + POFF) + goff0;
            int cc = c0;
#pragma unroll
            for (int st = 0; st < 5; ++st) {
                int chunk = st * 8 + wave;        // 0..39
                if (chunk < nch) load16_to_lds(gb, &tile[chunk * 256]);
                // advance by 2048 tile-dwords = 20 rows + 48 cols (mod 100)
                cc += 48;
                int wrap = (cc >= TW);
                cc = wrap ? cc - TW : cc;
                gb += 20 * PP + 48 + (wrap ? (PP - TW) : 0);
            }
        }
        __syncthreads();                 // RAW: staging visible
        {
            const float buL = buLb - (float)ub0;   // tile-local fold
            const float bvL = bvLb - (float)vb;
            const float fiw = (float)(ip + wave * 8) - c;
            float u = fmaf(au, fiw, buL);
            float v = fmaf(av, fiw, bvL);
#pragma unroll
            for (int k = 0; k < 8; ++k) {
                float wx = __builtin_amdgcn_fractf(u);
                float wy = __builtin_amdgcn_fractf(v);
                int iu = (int)u, iv = (int)v;      // trunc == floor (u,v > 0)
                int ai = iv * TW + iu;
                H2U P0, P1;
                P0.u = tile[ai];
                P1.u = tile[ai + TW];              // ds_read2_b32 0/100
                hh2 wy2 = cvt_pkrtz(wy, wy);
                hh2 m   = wy2 * (P1.h - P0.h) + P0.h;   // pk f16 vertical lerp
                hh2 wv  = cvt_pkrtz(1.0f - wx, wx);
                s = __builtin_amdgcn_fdot2(wv, m, s, false);
                u += au;                           // incremental (drift < 1e-4 px)
                v += av;
            }
        }
    }

    // ---- merge 8 wave-partials; plain store (sole owner of (d,a)) ----
    __syncthreads();
    float* ft = (float*)tile;
    ft[tid] = s;
    __syncthreads();
    if (tid < 64) {
        float r = ft[tid]       + ft[tid + 64]  + ft[tid + 128] + ft[tid + 192]
                + ft[tid + 256] + ft[tid + 320] + ft[tid + 384] + ft[tid + 448];
        out[(d0 + tid) * NA + a] = r;
    }
}

extern "C" void kernel_launch(void* const* d_in, const int* in_sizes, int n_in,
                              void* d_out, int out_size, void* d_ws, size_t ws_size,
                              hipStream_t stream) {
    const float* img  = (const float*)d_in[0];
    const int* angles = (const int*)d_in[1];
    float* out = (float*)d_out;
    float* ws  = (float*)d_ws;

    uint32_t* imgPB  = (uint32_t*)(ws + WS_IMGPB);
    uint32_t* imgTPB = (uint32_t*)(ws + WS_IMGTPB);
    float4*   tab    = (float4*)(ws + WS_TAB);
    int*      flags  = (int*)(ws + WS_FLAGS);

    dim3 pgrid(11, 11);
    pad_kernel<<<pgrid, 512, 0, stream>>>(img, angles, imgPB, imgTPB, tab, flags);

    dim3 grid(N / TD, NA);
    radon_kernel<<<grid, 512, 0, stream>>>(imgPB, imgTPB, tab, flags, out);
}